// Round 27
// baseline (71.257 us; speedup 1.0000x reference)
//
#include <hip/hip_runtime.h>

// Problem constants (b=8, h=w=32, m=8 heads, d=64, c=512)
#define Dd 64
#define Cc 512
#define HW 1024
#define BM 64            // b*m
#define LOG2E 1.44269504f

typedef __attribute__((ext_vector_type(8))) short bf16x8;
typedef __attribute__((ext_vector_type(4))) short bf16x4;
typedef __attribute__((ext_vector_type(4))) float f32x4;

__device__ __forceinline__ unsigned short f2bf(float f) {
  unsigned int u = __builtin_bit_cast(unsigned int, f);
  u += 0x7fffu + ((u >> 16) & 1u);
  return (unsigned short)(u >> 16);
}

// pack 2 fp32 -> 2 bf16 in one dword (scalar RNE pack — PROVEN; inline-asm
// v_cvt_pk_bf16_f32 produced garbage on this toolchain: R3-R6 NaNs)
__device__ __forceinline__ unsigned int pack2(float lo, float hi) {
  return (unsigned int)f2bf(lo) | ((unsigned int)f2bf(hi) << 16);
}

// 16B-granular XOR swizzle for [rows][64 bf16] LDS tiles (row stride 128B).
__device__ __forceinline__ int swz(int row, int cb) {
  return row * 128 + (cb ^ ((row & 7) << 4));
}

// ---------------------------------------------------------------------------
// K1 (R25 v3, unchanged): QKV as swapped MFMA GEMM, grid 512 (2 blocks/CU),
// W' staged once, 2 pos-groups. V written TRANSPOSED [bm][d][pos].
// ---------------------------------------------------------------------------
__global__ __launch_bounds__(256, 2) void qkv_kernel(
    const float* __restrict__ x, const float* __restrict__ w,
    const float* __restrict__ bqkv,
    unsigned short* __restrict__ Q, unsigned short* __restrict__ K,
    unsigned short* __restrict__ Vt) {
  __shared__ unsigned short Wt[192 * 64];  // [n'][k] swizzled
  __shared__ float bl[192];
  char* WtB = (char*)Wt;
  int t = threadIdx.x, lane = t & 63, wv = t >> 6;
  int c = lane & 15, r4 = lane >> 4;
  int bm = blockIdx.x >> 3;
  int chunk0 = (blockIdx.x & 7) * 128;
  int bb = bm >> 3, mm = bm & 7;

  for (int idx = t; idx < 12288; idx += 256) {
    int k = idx / 192, col = idx - (idx / 192) * 192;
    int d3 = col / 3, which = col - d3 * 3;
    int np = which * 64 + d3;
    float v = w[idx];
    if (which == 0) v *= 0.125f;  // q / sqrt(64)
    *(unsigned short*)(WtB + np * 128 + ((k * 2) ^ ((np & 7) << 4))) = f2bf(v);
  }
  if (t < 192) {
    int d3 = t / 3, which = t - d3 * 3;
    float bvv = bqkv[t];
    if (which == 0) bvv *= 0.125f;
    bl[which * 64 + d3] = bvv;
  }
  __syncthreads();

  bf16x8 af[12][2];
#pragma unroll
  for (int nf = 0; nf < 12; ++nf) {
    int row = nf * 16 + c, sw = (row & 7) << 4;
#pragma unroll
    for (int kc = 0; kc < 2; ++kc)
      af[nf][kc] = *(const bf16x8*)(WtB + row * 128 + ((kc * 64 + r4 * 16) ^ sw));
  }
  f32x4 bseed[12];
#pragma unroll
  for (int nf = 0; nf < 12; ++nf)
    bseed[nf] = *(const f32x4*)&bl[nf * 16 + r4 * 4];

#pragma unroll
  for (int pg = 0; pg < 2; ++pg) {
    int pos = chunk0 + pg * 64 + wv * 16 + c;
    const float* xr = x + (size_t)(bb * HW + pos) * Cc + mm * Dd;
    bf16x8 xb[2];
#pragma unroll
    for (int kc = 0; kc < 2; ++kc) {
      f32x4 lo = *(const f32x4*)(xr + kc * 32 + r4 * 8);
      f32x4 hi = *(const f32x4*)(xr + kc * 32 + r4 * 8 + 4);
      union { unsigned int u[4]; bf16x8 b; } cv;
      cv.u[0] = pack2(lo[0], lo[1]);
      cv.u[1] = pack2(lo[2], lo[3]);
      cv.u[2] = pack2(hi[0], hi[1]);
      cv.u[3] = pack2(hi[2], hi[3]);
      xb[kc] = cv.b;
    }
    f32x4 acc[12];
#pragma unroll
    for (int nf = 0; nf < 12; ++nf) {
      acc[nf] = bseed[nf];
      acc[nf] = __builtin_amdgcn_mfma_f32_16x16x32_bf16(af[nf][0], xb[0], acc[nf], 0, 0, 0);
      acc[nf] = __builtin_amdgcn_mfma_f32_16x16x32_bf16(af[nf][1], xb[1], acc[nf], 0, 0, 0);
    }
    size_t obase = ((size_t)bm * HW + pos) * Dd;
#pragma unroll
    for (int nf = 0; nf < 8; ++nf) {
      unsigned int d0 = pack2(acc[nf][0], acc[nf][1]);
      unsigned int d1 = pack2(acc[nf][2], acc[nf][3]);
      unsigned long long wd = (unsigned long long)d0 | ((unsigned long long)d1 << 32);
      unsigned short* dst = (nf < 4) ? Q : K;
      *(unsigned long long*)(dst + obase + (nf & 3) * 16 + r4 * 4) = wd;
    }
#pragma unroll
    for (int nf = 8; nf < 12; ++nf) {
#pragma unroll
      for (int reg = 0; reg < 4; ++reg) {
        int d = (nf - 8) * 16 + r4 * 4 + reg;
        Vt[((size_t)bm * Dd + d) * HW + pos] = f2bf(acc[nf][reg]);
      }
    }
  }
}

// ---------------------------------------------------------------------------
// K2 (R26 v10, unchanged — measured 40.2us): swapped QK^T flash attn,
// 64-row i-tiles, 4 blocks/CU, dbuf single-barrier, running bias pointers,
// max3 tree, defer-max.
// ---------------------------------------------------------------------------
__global__ __launch_bounds__(256, 4) void attn_kernel(
    const unsigned short* __restrict__ Q, const unsigned short* __restrict__ K,
    const unsigned short* __restrict__ Vt, const float* __restrict__ pe,
    unsigned short* __restrict__ O) {
  __shared__ unsigned short Kt[2][64 * 64];  // [buf][j][k] swizzled, 16KB
  __shared__ unsigned short Vl[2][64 * 64];  // [buf][d][j] swizzled, 16KB
  __shared__ unsigned short Pl[4][1024];     // per wave [i=c][j], 8KB
  char* PlB = (char*)Pl;
  int t = threadIdx.x, lane = t & 63, wv = t >> 6;
  int c = lane & 15, r4 = lane >> 4;
  int swzid = (blockIdx.x & 7) * 128 + (blockIdx.x >> 3);
  int bm = swzid >> 4;
  int i0 = (swzid & 15) * 64;

  const unsigned short* Qb = Q + ((size_t)bm * HW + i0 + wv * 16) * Dd;
  bf16x8 qb[2];
#pragma unroll
  for (int kc = 0; kc < 2; ++kc)
    qb[kc] = *(const bf16x8*)(Qb + c * Dd + kc * 32 + r4 * 8);

  int ibase = i0 + wv * 16;
  int yi = ibase >> 5, xib = ibase & 31;
  int hb = 63 * (31 - yi) + 31 - xib - c + r4 * 4;
  const float* pp0 = pe + hb;
  const float* pp1 = pp0 + 16;
  const float* pp2 = pp0 + 63;
  const float* pp3 = pp2 + 16;

  f32x4 oacc[4];
  float m_run = -1e30f, l_run = 0.f;
#pragma unroll
  for (int nf = 0; nf < 4; ++nf) oacc[nf] = {0.f, 0.f, 0.f, 0.f};

  const unsigned short* Kg = K + (size_t)bm * HW * Dd;
  const unsigned short* Vg = Vt + (size_t)bm * Dd * HW;
  char* pb = PlB + wv * 2048 + c * 128;
  int swp = (c & 7) << 4;
  int srow = t >> 3, sc8 = t & 7;

  bf16x8 kreg[2], vreg[2];
  auto issue = [&](int j0) {
#pragma unroll
    for (int rep = 0; rep < 2; ++rep) {
      int row = srow + rep * 32;
      kreg[rep] = *(const bf16x8*)(Kg + (size_t)(j0 + row) * Dd + sc8 * 8);
      vreg[rep] = *(const bf16x8*)(Vg + (size_t)row * HW + j0 + sc8 * 8);
    }
  };
  auto stage = [&](int buf) {
#pragma unroll
    for (int rep = 0; rep < 2; ++rep) {
      int row = srow + rep * 32;
      *(bf16x8*)((char*)Kt[buf] + swz(row, sc8 * 16)) = kreg[rep];
      *(bf16x8*)((char*)Vl[buf] + swz(row, sc8 * 16)) = vreg[rep];
    }
  };

  issue(0);
  stage(0);
  issue(64);
  __syncthreads();

  int cur = 0;
  for (int jt = 0; jt < 16; ++jt) {
    int j0 = jt * 64;
    if (jt < 15) {
      stage(cur ^ 1);
      if (jt < 14) issue(j0 + 128);
    }
    char* KtB = (char*)Kt[cur];
    char* VtB = (char*)Vl[cur];

    f32x4 sacc[4];
    sacc[0] = {pp0[0], pp0[1], pp0[2], pp0[3]};
    sacc[1] = {pp1[0], pp1[1], pp1[2], pp1[3]};
    sacc[2] = {pp2[0], pp2[1], pp2[2], pp2[3]};
    sacc[3] = {pp3[0], pp3[1], pp3[2], pp3[3]};
    pp0 += 126; pp1 += 126; pp2 += 126; pp3 += 126;
#pragma unroll
    for (int jf = 0; jf < 4; ++jf) {
      int row = jf * 16 + c, sw = (row & 7) << 4;
      bf16x8 kb0 = *(const bf16x8*)(KtB + row * 128 + ((r4 * 16) ^ sw));
      bf16x8 kb1 = *(const bf16x8*)(KtB + row * 128 + ((64 + r4 * 16) ^ sw));
      sacc[jf] = __builtin_amdgcn_mfma_f32_16x16x32_bf16(kb0, qb[0], sacc[jf], 0, 0, 0);
      sacc[jf] = __builtin_amdgcn_mfma_f32_16x16x32_bf16(kb1, qb[1], sacc[jf], 0, 0, 0);
    }
    float m0 = fmaxf(fmaxf(sacc[0][0], sacc[0][1]), sacc[0][2]);
    float m1 = fmaxf(fmaxf(sacc[0][3], sacc[1][0]), sacc[1][1]);
    float m2 = fmaxf(fmaxf(sacc[1][2], sacc[1][3]), sacc[2][0]);
    float m3 = fmaxf(fmaxf(sacc[2][1], sacc[2][2]), sacc[2][3]);
    float m4 = fmaxf(fmaxf(sacc[3][0], sacc[3][1]), sacc[3][2]);
    float mx = fmaxf(fmaxf(fmaxf(m0, m1), m2),
                     fmaxf(fmaxf(m3, m4), sacc[3][3]));
    mx = fmaxf(mx, __shfl_xor(mx, 16));
    mx = fmaxf(mx, __shfl_xor(mx, 32));
    if (!__all(mx <= m_run + 8.f)) {  // T13 defer-max
      float mnew = fmaxf(m_run, mx);
      float sc = __builtin_amdgcn_exp2f((m_run - mnew) * LOG2E);
      m_run = mnew;
      l_run *= sc;
#pragma unroll
      for (int nf = 0; nf < 4; ++nf) oacc[nf] *= sc;
    }
    float ml = m_run * LOG2E;
    float ps = 0.f;
#pragma unroll
    for (int jf = 0; jf < 4; ++jf)
#pragma unroll
      for (int r = 0; r < 4; ++r) {
        float p = __builtin_amdgcn_exp2f(fmaf(sacc[jf][r], LOG2E, -ml));
        sacc[jf][r] = p;
        ps += p;
      }
    ps += __shfl_xor(ps, 16);
    ps += __shfl_xor(ps, 32);
    l_run += ps;
#pragma unroll
    for (int jf = 0; jf < 4; ++jf) {
      unsigned int w0 = pack2(sacc[jf][0], sacc[jf][1]);
      unsigned int w1 = pack2(sacc[jf][2], sacc[jf][3]);
      unsigned long long wd = (unsigned long long)w0 | ((unsigned long long)w1 << 32);
      *(unsigned long long*)(pb + ((jf * 32 + r4 * 8) ^ swp)) = wd;
    }
#pragma unroll
    for (int jk = 0; jk < 2; ++jk) {
      bf16x8 pa = *(const bf16x8*)(pb + ((jk * 64 + r4 * 16) ^ swp));
#pragma unroll
      for (int nf = 0; nf < 4; ++nf) {
        int row = nf * 16 + c, sw = (row & 7) << 4;
        bf16x8 vb = *(const bf16x8*)(VtB + row * 128 + ((jk * 64 + r4 * 16) ^ sw));
        oacc[nf] = __builtin_amdgcn_mfma_f32_16x16x32_bf16(vb, pa, oacc[nf], 0, 0, 0);
      }
    }
    if (jt < 15) {
      __syncthreads();
      cur ^= 1;
    }
  }

  __syncthreads();
  char* zone = ((wv < 2) ? (char*)Kt[0] : (char*)Vl[0]) + (wv & 1) * 4096;
  float inv = 1.f / l_run;
  int swc = (c & 7) << 4;
#pragma unroll
  for (int nf = 0; nf < 4; ++nf) {
    unsigned int d0 = pack2(oacc[nf][0] * inv, oacc[nf][1] * inv);
    unsigned int d1 = pack2(oacc[nf][2] * inv, oacc[nf][3] * inv);
    unsigned long long wd = (unsigned long long)d0 | ((unsigned long long)d1 << 32);
    *(unsigned long long*)(zone + c * 128 + ((nf * 32 + r4 * 8) ^ swc)) = wd;
  }
  __syncthreads();
  int rrow = lane >> 2, dq = lane & 3;
  int swr = (rrow & 7) << 4;
  size_t obase = ((size_t)bm * HW + i0 + wv * 16 + rrow) * Dd + dq * 16;
#pragma unroll
  for (int p = 0; p < 2; ++p) {
    bf16x8 vv = *(const bf16x8*)(zone + rrow * 128 + ((dq * 32 + p * 16) ^ swr));
    *(bf16x8*)(O + obase + p * 8) = vv;
  }
}

// ---------------------------------------------------------------------------
// K3 (v6 = v5 at 64-row blocks for 4 blocks/CU): output projection. proj's
// direct-global A loads were latency-exposed at 2 blocks/CU; halving the
// row-block doubles resident blocks. XCD-locality kept: block = nb*128+rb,
// XCD = rb%8 for all 8 nb sharing rb's O-rows. LDS 16KB.
// ---------------------------------------------------------------------------
__global__ __launch_bounds__(256, 4) void proj_kernel(
    const unsigned short* __restrict__ O, const float* __restrict__ W,
    const float* __restrict__ bias, float* __restrict__ out) {
  __shared__ unsigned short Bt[2][64 * 64];   // [buf][n][k] swizzled, 16KB
  int t = threadIdx.x, lane = t & 63, wv = t >> 6;
  int rb = blockIdx.x & 127, n0 = (blockIdx.x >> 7) * 64;
  int row0 = rb * 64;              // flat (b,pos); never crosses b (64|1024)
  int b = row0 >> 10, pos0 = row0 & 1023;
  int c = lane & 15, r4 = lane >> 4;
  int nt = t & 15, kt = t >> 4;

  f32x4 acc[4];
#pragma unroll
  for (int nf = 0; nf < 4; ++nf) acc[nf] = {0.f, 0.f, 0.f, 0.f};

  f32x4 wreg[4];
  bf16x8 aA[2], aB[2];  // A-frag dbuf: [kc] for row wv*16+c

  auto issueW = [&](int m) {
#pragma unroll
    for (int r = 0; r < 4; ++r)
      wreg[r] = *(const f32x4*)(W + (size_t)(m * 64 + kt * 4 + r) * Cc + n0 + nt * 4);
  };
  auto issueA = [&](bf16x8 (&ar)[2], int m) {
    const unsigned short* Ob = O + ((size_t)(b * 8 + m) * HW + pos0) * Dd;
#pragma unroll
    for (int kc = 0; kc < 2; ++kc)
      ar[kc] = *(const bf16x8*)(Ob + (size_t)(wv * 16 + c) * Dd + kc * 32 + r4 * 8);
  };
  auto stageB = [&](int buf) {
    char* BtB = (char*)Bt[buf];
#pragma unroll
    for (int e = 0; e < 4; ++e) {
      bf16x4 bt = {(short)f2bf(wreg[0][e]), (short)f2bf(wreg[1][e]),
                   (short)f2bf(wreg[2][e]), (short)f2bf(wreg[3][e])};
      *(bf16x4*)(BtB + swz(nt * 4 + e, kt * 8)) = bt;
    }
  };

  issueW(0);
  issueA(aA, 0);
  stageB(0);
  issueW(1);
  issueA(aB, 1);
  __syncthreads();

  int cur = 0;
  for (int m = 0; m < 8; ++m) {
    if (m < 7) {
      stageB(cur ^ 1);
      if (m < 6) issueW(m + 2);
    }
    char* BtB = (char*)Bt[cur];
    bf16x8* ar = (m & 1) ? aB : aA;
#pragma unroll
    for (int kc = 0; kc < 2; ++kc) {
#pragma unroll
      for (int nf = 0; nf < 4; ++nf) {
        bf16x8 bb = *(const bf16x8*)(BtB + swz(nf * 16 + c, kc * 64 + r4 * 16));
        acc[nf] = __builtin_amdgcn_mfma_f32_16x16x32_bf16(ar[kc], bb, acc[nf], 0, 0, 0);
      }
    }
    if (m < 6) issueA((m & 1) ? aB : aA, m + 2);  // prefetch A for m+2
    if (m < 7) {
      __syncthreads();
      cur ^= 1;
    }
  }

  float bv[4];
#pragma unroll
  for (int nf = 0; nf < 4; ++nf) bv[nf] = bias[n0 + nf * 16 + c];
#pragma unroll
  for (int reg = 0; reg < 4; ++reg) {
    int row = row0 + wv * 16 + r4 * 4 + reg;
#pragma unroll
    for (int nf = 0; nf < 4; ++nf)
      out[(size_t)row * Cc + n0 + nf * 16 + c] = acc[nf][reg] + bv[nf];
  }
}

extern "C" void kernel_launch(void* const* d_in, const int* in_sizes, int n_in,
                              void* d_out, int out_size, void* d_ws, size_t ws_size,
                              hipStream_t stream) {
  const float* x      = (const float*)d_in[0];
  const float* qkv_w  = (const float*)d_in[1];
  const float* qkv_b  = (const float*)d_in[2];
  const float* pos_emb= (const float*)d_in[3];
  const float* ht_w   = (const float*)d_in[4];
  const float* ht_b   = (const float*)d_in[5];
  float* out = (float*)d_out;

  const size_t NQ = (size_t)BM * HW * Dd;  // 4,194,304 elements
  unsigned short* Qw  = (unsigned short*)d_ws;
  unsigned short* Kw  = Qw + NQ;
  unsigned short* Vtw = Kw + NQ;           // V^T [bm][d][pos], 8 MB
  unsigned short* Ow  = Vtw + NQ;          // bf16 O [bm][pos][d], 8 MB

  hipLaunchKernelGGL(qkv_kernel, dim3(512), dim3(256), 0, stream,
                     x, qkv_w, qkv_b, Qw, Kw, Vtw);
  hipLaunchKernelGGL(attn_kernel, dim3(1024), dim3(256), 0, stream,
                     Qw, Kw, Vtw, pos_emb, Ow);
  hipLaunchKernelGGL(proj_kernel, dim3(1024), dim3(256), 0, stream,
                     Ow, ht_w, ht_b, out);
}

// Round 28
// 68.426 us; speedup vs baseline: 1.0414x; 1.0414x over previous
//
#include <hip/hip_runtime.h>

// Problem constants (b=8, h=w=32, m=8 heads, d=64, c=512)
#define Dd 64
#define Cc 512
#define HW 1024
#define BM 64            // b*m
#define LOG2E 1.44269504f

typedef __attribute__((ext_vector_type(8))) short bf16x8;
typedef __attribute__((ext_vector_type(4))) short bf16x4;
typedef __attribute__((ext_vector_type(4))) float f32x4;

__device__ __forceinline__ unsigned short f2bf(float f) {
  unsigned int u = __builtin_bit_cast(unsigned int, f);
  u += 0x7fffu + ((u >> 16) & 1u);
  return (unsigned short)(u >> 16);
}

// pack 2 fp32 -> 2 bf16 in one dword (scalar RNE pack — PROVEN; inline-asm
// v_cvt_pk_bf16_f32 produced garbage on this toolchain: R3-R6 NaNs)
__device__ __forceinline__ unsigned int pack2(float lo, float hi) {
  return (unsigned int)f2bf(lo) | ((unsigned int)f2bf(hi) << 16);
}

// 16B-granular XOR swizzle for [rows][64 bf16] LDS tiles (row stride 128B).
__device__ __forceinline__ int swz(int row, int cb) {
  return row * 128 + (cb ^ ((row & 7) << 4));
}

// ---------------------------------------------------------------------------
// K1 (R25 v3): QKV as swapped MFMA GEMM, grid 512 (2 blocks/CU),
// W' staged once, 2 pos-groups. V written TRANSPOSED [bm][d][pos].
// ---------------------------------------------------------------------------
__global__ __launch_bounds__(256, 2) void qkv_kernel(
    const float* __restrict__ x, const float* __restrict__ w,
    const float* __restrict__ bqkv,
    unsigned short* __restrict__ Q, unsigned short* __restrict__ K,
    unsigned short* __restrict__ Vt) {
  __shared__ unsigned short Wt[192 * 64];  // [n'][k] swizzled
  __shared__ float bl[192];
  char* WtB = (char*)Wt;
  int t = threadIdx.x, lane = t & 63, wv = t >> 6;
  int c = lane & 15, r4 = lane >> 4;
  int bm = blockIdx.x >> 3;
  int chunk0 = (blockIdx.x & 7) * 128;
  int bb = bm >> 3, mm = bm & 7;

  for (int idx = t; idx < 12288; idx += 256) {
    int k = idx / 192, col = idx - (idx / 192) * 192;
    int d3 = col / 3, which = col - d3 * 3;
    int np = which * 64 + d3;
    float v = w[idx];
    if (which == 0) v *= 0.125f;  // q / sqrt(64)
    *(unsigned short*)(WtB + np * 128 + ((k * 2) ^ ((np & 7) << 4))) = f2bf(v);
  }
  if (t < 192) {
    int d3 = t / 3, which = t - d3 * 3;
    float bvv = bqkv[t];
    if (which == 0) bvv *= 0.125f;
    bl[which * 64 + d3] = bvv;
  }
  __syncthreads();

  bf16x8 af[12][2];
#pragma unroll
  for (int nf = 0; nf < 12; ++nf) {
    int row = nf * 16 + c, sw = (row & 7) << 4;
#pragma unroll
    for (int kc = 0; kc < 2; ++kc)
      af[nf][kc] = *(const bf16x8*)(WtB + row * 128 + ((kc * 64 + r4 * 16) ^ sw));
  }
  f32x4 bseed[12];
#pragma unroll
  for (int nf = 0; nf < 12; ++nf)
    bseed[nf] = *(const f32x4*)&bl[nf * 16 + r4 * 4];

#pragma unroll
  for (int pg = 0; pg < 2; ++pg) {
    int pos = chunk0 + pg * 64 + wv * 16 + c;
    const float* xr = x + (size_t)(bb * HW + pos) * Cc + mm * Dd;
    bf16x8 xb[2];
#pragma unroll
    for (int kc = 0; kc < 2; ++kc) {
      f32x4 lo = *(const f32x4*)(xr + kc * 32 + r4 * 8);
      f32x4 hi = *(const f32x4*)(xr + kc * 32 + r4 * 8 + 4);
      union { unsigned int u[4]; bf16x8 b; } cv;
      cv.u[0] = pack2(lo[0], lo[1]);
      cv.u[1] = pack2(lo[2], lo[3]);
      cv.u[2] = pack2(hi[0], hi[1]);
      cv.u[3] = pack2(hi[2], hi[3]);
      xb[kc] = cv.b;
    }
    f32x4 acc[12];
#pragma unroll
    for (int nf = 0; nf < 12; ++nf) {
      acc[nf] = bseed[nf];
      acc[nf] = __builtin_amdgcn_mfma_f32_16x16x32_bf16(af[nf][0], xb[0], acc[nf], 0, 0, 0);
      acc[nf] = __builtin_amdgcn_mfma_f32_16x16x32_bf16(af[nf][1], xb[1], acc[nf], 0, 0, 0);
    }
    size_t obase = ((size_t)bm * HW + pos) * Dd;
#pragma unroll
    for (int nf = 0; nf < 8; ++nf) {
      unsigned int d0 = pack2(acc[nf][0], acc[nf][1]);
      unsigned int d1 = pack2(acc[nf][2], acc[nf][3]);
      unsigned long long wd = (unsigned long long)d0 | ((unsigned long long)d1 << 32);
      unsigned short* dst = (nf < 4) ? Q : K;
      *(unsigned long long*)(dst + obase + (nf & 3) * 16 + r4 * 4) = wd;
    }
#pragma unroll
    for (int nf = 8; nf < 12; ++nf) {
#pragma unroll
      for (int reg = 0; reg < 4; ++reg) {
        int d = (nf - 8) * 16 + r4 * 4 + reg;
        Vt[((size_t)bm * Dd + d) * HW + pos] = f2bf(acc[nf][reg]);
      }
    }
  }
}

// ---------------------------------------------------------------------------
// K2 (R26 v10 — measured 40.2us): swapped QK^T flash attn, 64-row i-tiles,
// 4 blocks/CU, dbuf single-barrier, running bias pointers, max3 tree,
// defer-max.
// ---------------------------------------------------------------------------
__global__ __launch_bounds__(256, 4) void attn_kernel(
    const unsigned short* __restrict__ Q, const unsigned short* __restrict__ K,
    const unsigned short* __restrict__ Vt, const float* __restrict__ pe,
    unsigned short* __restrict__ O) {
  __shared__ unsigned short Kt[2][64 * 64];  // [buf][j][k] swizzled, 16KB
  __shared__ unsigned short Vl[2][64 * 64];  // [buf][d][j] swizzled, 16KB
  __shared__ unsigned short Pl[4][1024];     // per wave [i=c][j], 8KB
  char* PlB = (char*)Pl;
  int t = threadIdx.x, lane = t & 63, wv = t >> 6;
  int c = lane & 15, r4 = lane >> 4;
  int swzid = (blockIdx.x & 7) * 128 + (blockIdx.x >> 3);
  int bm = swzid >> 4;
  int i0 = (swzid & 15) * 64;

  const unsigned short* Qb = Q + ((size_t)bm * HW + i0 + wv * 16) * Dd;
  bf16x8 qb[2];
#pragma unroll
  for (int kc = 0; kc < 2; ++kc)
    qb[kc] = *(const bf16x8*)(Qb + c * Dd + kc * 32 + r4 * 8);

  int ibase = i0 + wv * 16;
  int yi = ibase >> 5, xib = ibase & 31;
  int hb = 63 * (31 - yi) + 31 - xib - c + r4 * 4;
  const float* pp0 = pe + hb;
  const float* pp1 = pp0 + 16;
  const float* pp2 = pp0 + 63;
  const float* pp3 = pp2 + 16;

  f32x4 oacc[4];
  float m_run = -1e30f, l_run = 0.f;
#pragma unroll
  for (int nf = 0; nf < 4; ++nf) oacc[nf] = {0.f, 0.f, 0.f, 0.f};

  const unsigned short* Kg = K + (size_t)bm * HW * Dd;
  const unsigned short* Vg = Vt + (size_t)bm * Dd * HW;
  char* pb = PlB + wv * 2048 + c * 128;
  int swp = (c & 7) << 4;
  int srow = t >> 3, sc8 = t & 7;

  bf16x8 kreg[2], vreg[2];
  auto issue = [&](int j0) {
#pragma unroll
    for (int rep = 0; rep < 2; ++rep) {
      int row = srow + rep * 32;
      kreg[rep] = *(const bf16x8*)(Kg + (size_t)(j0 + row) * Dd + sc8 * 8);
      vreg[rep] = *(const bf16x8*)(Vg + (size_t)row * HW + j0 + sc8 * 8);
    }
  };
  auto stage = [&](int buf) {
#pragma unroll
    for (int rep = 0; rep < 2; ++rep) {
      int row = srow + rep * 32;
      *(bf16x8*)((char*)Kt[buf] + swz(row, sc8 * 16)) = kreg[rep];
      *(bf16x8*)((char*)Vl[buf] + swz(row, sc8 * 16)) = vreg[rep];
    }
  };

  issue(0);
  stage(0);
  issue(64);
  __syncthreads();

  int cur = 0;
  for (int jt = 0; jt < 16; ++jt) {
    int j0 = jt * 64;
    if (jt < 15) {
      stage(cur ^ 1);
      if (jt < 14) issue(j0 + 128);
    }
    char* KtB = (char*)Kt[cur];
    char* VtB = (char*)Vl[cur];

    f32x4 sacc[4];
    sacc[0] = {pp0[0], pp0[1], pp0[2], pp0[3]};
    sacc[1] = {pp1[0], pp1[1], pp1[2], pp1[3]};
    sacc[2] = {pp2[0], pp2[1], pp2[2], pp2[3]};
    sacc[3] = {pp3[0], pp3[1], pp3[2], pp3[3]};
    pp0 += 126; pp1 += 126; pp2 += 126; pp3 += 126;
#pragma unroll
    for (int jf = 0; jf < 4; ++jf) {
      int row = jf * 16 + c, sw = (row & 7) << 4;
      bf16x8 kb0 = *(const bf16x8*)(KtB + row * 128 + ((r4 * 16) ^ sw));
      bf16x8 kb1 = *(const bf16x8*)(KtB + row * 128 + ((64 + r4 * 16) ^ sw));
      sacc[jf] = __builtin_amdgcn_mfma_f32_16x16x32_bf16(kb0, qb[0], sacc[jf], 0, 0, 0);
      sacc[jf] = __builtin_amdgcn_mfma_f32_16x16x32_bf16(kb1, qb[1], sacc[jf], 0, 0, 0);
    }
    float m0 = fmaxf(fmaxf(sacc[0][0], sacc[0][1]), sacc[0][2]);
    float m1 = fmaxf(fmaxf(sacc[0][3], sacc[1][0]), sacc[1][1]);
    float m2 = fmaxf(fmaxf(sacc[1][2], sacc[1][3]), sacc[2][0]);
    float m3 = fmaxf(fmaxf(sacc[2][1], sacc[2][2]), sacc[2][3]);
    float m4 = fmaxf(fmaxf(sacc[3][0], sacc[3][1]), sacc[3][2]);
    float mx = fmaxf(fmaxf(fmaxf(m0, m1), m2),
                     fmaxf(fmaxf(m3, m4), sacc[3][3]));
    mx = fmaxf(mx, __shfl_xor(mx, 16));
    mx = fmaxf(mx, __shfl_xor(mx, 32));
    if (!__all(mx <= m_run + 8.f)) {  // T13 defer-max
      float mnew = fmaxf(m_run, mx);
      float sc = __builtin_amdgcn_exp2f((m_run - mnew) * LOG2E);
      m_run = mnew;
      l_run *= sc;
#pragma unroll
      for (int nf = 0; nf < 4; ++nf) oacc[nf] *= sc;
    }
    float ml = m_run * LOG2E;
    float ps = 0.f;
#pragma unroll
    for (int jf = 0; jf < 4; ++jf)
#pragma unroll
      for (int r = 0; r < 4; ++r) {
        float p = __builtin_amdgcn_exp2f(fmaf(sacc[jf][r], LOG2E, -ml));
        sacc[jf][r] = p;
        ps += p;
      }
    ps += __shfl_xor(ps, 16);
    ps += __shfl_xor(ps, 32);
    l_run += ps;
#pragma unroll
    for (int jf = 0; jf < 4; ++jf) {
      unsigned int w0 = pack2(sacc[jf][0], sacc[jf][1]);
      unsigned int w1 = pack2(sacc[jf][2], sacc[jf][3]);
      unsigned long long wd = (unsigned long long)w0 | ((unsigned long long)w1 << 32);
      *(unsigned long long*)(pb + ((jf * 32 + r4 * 8) ^ swp)) = wd;
    }
#pragma unroll
    for (int jk = 0; jk < 2; ++jk) {
      bf16x8 pa = *(const bf16x8*)(pb + ((jk * 64 + r4 * 16) ^ swp));
#pragma unroll
      for (int nf = 0; nf < 4; ++nf) {
        int row = nf * 16 + c, sw = (row & 7) << 4;
        bf16x8 vb = *(const bf16x8*)(VtB + row * 128 + ((jk * 64 + r4 * 16) ^ sw));
        oacc[nf] = __builtin_amdgcn_mfma_f32_16x16x32_bf16(vb, pa, oacc[nf], 0, 0, 0);
      }
    }
    if (jt < 15) {
      __syncthreads();
      cur ^= 1;
    }
  }

  __syncthreads();
  char* zone = ((wv < 2) ? (char*)Kt[0] : (char*)Vl[0]) + (wv & 1) * 4096;
  float inv = 1.f / l_run;
  int swc = (c & 7) << 4;
#pragma unroll
  for (int nf = 0; nf < 4; ++nf) {
    unsigned int d0 = pack2(oacc[nf][0] * inv, oacc[nf][1] * inv);
    unsigned int d1 = pack2(oacc[nf][2] * inv, oacc[nf][3] * inv);
    unsigned long long wd = (unsigned long long)d0 | ((unsigned long long)d1 << 32);
    *(unsigned long long*)(zone + c * 128 + ((nf * 32 + r4 * 8) ^ swc)) = wd;
  }
  __syncthreads();
  int rrow = lane >> 2, dq = lane & 3;
  int swr = (rrow & 7) << 4;
  size_t obase = ((size_t)bm * HW + i0 + wv * 16 + rrow) * Dd + dq * 16;
#pragma unroll
  for (int p = 0; p < 2; ++p) {
    bf16x8 vv = *(const bf16x8*)(zone + rrow * 128 + ((dq * 32 + p * 16) ^ swr));
    *(bf16x8*)(O + obase + p * 8) = vv;
  }
}

// ---------------------------------------------------------------------------
// K3 (R26 v5 — best measured): output projection, 128 rows x 64 n.
// rb = blockIdx&63, nb = blockIdx>>6: all 8 n-blocks sharing one rb's
// O-rows land on XCD rb%8 -> 7/8 O reads are local L2 hits.
// ---------------------------------------------------------------------------
__global__ __launch_bounds__(256, 2) void proj_kernel(
    const unsigned short* __restrict__ O, const float* __restrict__ W,
    const float* __restrict__ bias, float* __restrict__ out) {
  __shared__ unsigned short Bt[2][64 * 64];   // [buf][n][k] swizzled, 16KB
  int t = threadIdx.x, lane = t & 63, wv = t >> 6;
  int rb = blockIdx.x & 63, n0 = (blockIdx.x >> 6) * 64;
  int row0 = rb * 128;
  int b = row0 >> 10, pos0 = row0 & 1023;
  int c = lane & 15, r4 = lane >> 4;
  int nt = t & 15, kt = t >> 4;

  f32x4 acc[2][4];
#pragma unroll
  for (int g = 0; g < 2; ++g)
#pragma unroll
    for (int nf = 0; nf < 4; ++nf) acc[g][nf] = {0.f, 0.f, 0.f, 0.f};

  f32x4 wreg[4];
  bf16x8 aA[4], aB[4];

  auto issueW = [&](int m) {
#pragma unroll
    for (int r = 0; r < 4; ++r)
      wreg[r] = *(const f32x4*)(W + (size_t)(m * 64 + kt * 4 + r) * Cc + n0 + nt * 4);
  };
  auto issueA = [&](bf16x8 (&ar)[4], int m) {
    const unsigned short* Ob = O + ((size_t)(b * 8 + m) * HW + pos0) * Dd;
#pragma unroll
    for (int g = 0; g < 2; ++g)
#pragma unroll
      for (int kc = 0; kc < 2; ++kc)
        ar[g * 2 + kc] = *(const bf16x8*)(Ob + (size_t)(wv * 32 + g * 16 + c) * Dd +
                                          kc * 32 + r4 * 8);
  };
  auto stageB = [&](int buf) {
    char* BtB = (char*)Bt[buf];
#pragma unroll
    for (int e = 0; e < 4; ++e) {
      bf16x4 bt = {(short)f2bf(wreg[0][e]), (short)f2bf(wreg[1][e]),
                   (short)f2bf(wreg[2][e]), (short)f2bf(wreg[3][e])};
      *(bf16x4*)(BtB + swz(nt * 4 + e, kt * 8)) = bt;
    }
  };

  issueW(0);
  issueA(aA, 0);
  stageB(0);
  issueW(1);
  issueA(aB, 1);
  __syncthreads();

  int cur = 0;
  for (int m = 0; m < 8; ++m) {
    if (m < 7) {
      stageB(cur ^ 1);
      if (m < 6) issueW(m + 2);
    }
    char* BtB = (char*)Bt[cur];
    bf16x8* ar = (m & 1) ? aB : aA;
#pragma unroll
    for (int kc = 0; kc < 2; ++kc) {
#pragma unroll
      for (int nf = 0; nf < 4; ++nf) {
        bf16x8 bb = *(const bf16x8*)(BtB + swz(nf * 16 + c, kc * 64 + r4 * 16));
        acc[0][nf] = __builtin_amdgcn_mfma_f32_16x16x32_bf16(ar[kc], bb, acc[0][nf], 0, 0, 0);
        acc[1][nf] = __builtin_amdgcn_mfma_f32_16x16x32_bf16(ar[2 + kc], bb, acc[1][nf], 0, 0, 0);
      }
    }
    if (m < 6) issueA((m & 1) ? aB : aA, m + 2);
    if (m < 7) {
      __syncthreads();
      cur ^= 1;
    }
  }

  float bv[4];
#pragma unroll
  for (int nf = 0; nf < 4; ++nf) bv[nf] = bias[n0 + nf * 16 + c];
#pragma unroll
  for (int g = 0; g < 2; ++g) {
#pragma unroll
    for (int reg = 0; reg < 4; ++reg) {
      int row = row0 + wv * 32 + g * 16 + r4 * 4 + reg;
#pragma unroll
      for (int nf = 0; nf < 4; ++nf)
        out[(size_t)row * Cc + n0 + nf * 16 + c] = acc[g][nf][reg] + bv[nf];
    }
  }
}

extern "C" void kernel_launch(void* const* d_in, const int* in_sizes, int n_in,
                              void* d_out, int out_size, void* d_ws, size_t ws_size,
                              hipStream_t stream) {
  const float* x      = (const float*)d_in[0];
  const float* qkv_w  = (const float*)d_in[1];
  const float* qkv_b  = (const float*)d_in[2];
  const float* pos_emb= (const float*)d_in[3];
  const float* ht_w   = (const float*)d_in[4];
  const float* ht_b   = (const float*)d_in[5];
  float* out = (float*)d_out;

  const size_t NQ = (size_t)BM * HW * Dd;  // 4,194,304 elements
  unsigned short* Qw  = (unsigned short*)d_ws;
  unsigned short* Kw  = Qw + NQ;
  unsigned short* Vtw = Kw + NQ;           // V^T [bm][d][pos], 8 MB
  unsigned short* Ow  = Vtw + NQ;          // bf16 O [bm][pos][d], 8 MB

  hipLaunchKernelGGL(qkv_kernel, dim3(512), dim3(256), 0, stream,
                     x, qkv_w, qkv_b, Qw, Kw, Vtw);
  hipLaunchKernelGGL(attn_kernel, dim3(1024), dim3(256), 0, stream,
                     Qw, Kw, Vtw, pos_emb, Ow);
  hipLaunchKernelGGL(proj_kernel, dim3(512), dim3(256), 0, stream,
                     Ow, ht_w, ht_b, out);
}